// Round 1
// baseline (3092.861 us; speedup 1.0000x reference)
//
#include <hip/hip_runtime.h>

#define NN 100000
#define NE 1600000

// ---------------------------------------------------------------------------
// k1: h = X @ W  (fp32, W in LDS, 4 rows x 32 cols per thread)
//     + fused per-node attention partial dots:
//       asrc[n,h] = dot(h[n,h,:], a[h,0:32]),  adst[n,h] = dot(h[n,h,:], a[h,32:64])
// ---------------------------------------------------------------------------
__global__ __launch_bounds__(256) void k1_gemm_alpha(
    const float* __restrict__ X, const float* __restrict__ W,
    const float* __restrict__ a, float* __restrict__ hout,
    float* __restrict__ asrc, float* __restrict__ adst)
{
    __shared__ float sW[128 * 128];  // 64 KB, swizzled
    {
        const float4* W4 = (const float4*)W;
        float4* sW4 = (float4*)sW;
        #pragma unroll
        for (int i = 0; i < 16; ++i) {
            int idx = threadIdx.x + i * 256;   // 0..4095 float4 granules
            int cg  = idx & 31;                // col granule within k-row
            int k   = idx >> 5;
            int cgs = cg ^ ((cg >> 3) & 3);    // bank swizzle (per col-quarter)
            sW4[(k << 5) + cgs] = W4[idx];
        }
    }
    __syncthreads();

    const int q  = threadIdx.x & 3;   // head / col-quarter (cols q*32..q*32+31)
    const int rg = threadIdx.x >> 2;  // 0..63
    const int row0 = blockIdx.x * 256;

    int rows[4];
    const float4* x4[4];
    #pragma unroll
    for (int i = 0; i < 4; ++i) {
        int r = row0 + rg + i * 64;
        rows[i] = r;
        int rc = r < NN ? r : (NN - 1);
        x4[i] = (const float4*)(X + (size_t)rc * 128);
    }

    float acc[4][32];
    #pragma unroll
    for (int i = 0; i < 4; ++i) {
        #pragma unroll
        for (int c = 0; c < 32; ++c) acc[i][c] = 0.f;
    }

    const float4* sW4r = (const float4*)sW;
    for (int k4 = 0; k4 < 32; ++k4) {
        float xs[4][4];
        #pragma unroll
        for (int i = 0; i < 4; ++i) {
            float4 xv = x4[i][k4];
            xs[i][0] = xv.x; xs[i][1] = xv.y; xs[i][2] = xv.z; xs[i][3] = xv.w;
        }
        #pragma unroll
        for (int j = 0; j < 4; ++j) {
            const int k = (k4 << 2) + j;
            const float4* wr = sW4r + (k << 5) + (q << 3);
            #pragma unroll
            for (int c = 0; c < 8; ++c) {
                float4 wv = wr[c ^ q];  // un-swizzle: logical granule c
                #pragma unroll
                for (int i = 0; i < 4; ++i) {
                    acc[i][(c << 2) + 0] = fmaf(xs[i][j], wv.x, acc[i][(c << 2) + 0]);
                    acc[i][(c << 2) + 1] = fmaf(xs[i][j], wv.y, acc[i][(c << 2) + 1]);
                    acc[i][(c << 2) + 2] = fmaf(xs[i][j], wv.z, acc[i][(c << 2) + 2]);
                    acc[i][(c << 2) + 3] = fmaf(xs[i][j], wv.w, acc[i][(c << 2) + 3]);
                }
            }
        }
    }

    // stage 'a' (256 floats) into LDS (reuse sW; all k-loop reads are done)
    __syncthreads();
    sW[threadIdx.x] = a[threadIdx.x];
    __syncthreads();
    const float* av = sW + q * 64;

    #pragma unroll
    for (int i = 0; i < 4; ++i) {
        if (rows[i] >= NN) continue;
        float ssrc = 0.f, sdst = 0.f;
        #pragma unroll
        for (int c = 0; c < 32; ++c) {
            ssrc = fmaf(acc[i][c], av[c], ssrc);
            sdst = fmaf(acc[i][c], av[32 + c], sdst);
        }
        float* hr = hout + (size_t)rows[i] * 128 + q * 32;
        #pragma unroll
        for (int c = 0; c < 8; ++c) {
            ((float4*)hr)[c] = make_float4(acc[i][(c << 2) + 0], acc[i][(c << 2) + 1],
                                           acc[i][(c << 2) + 2], acc[i][(c << 2) + 3]);
        }
        asrc[rows[i] * 4 + q] = ssrc;
        adst[rows[i] * 4 + q] = sdst;
    }
}

// ---------------------------------------------------------------------------
// k2: per-edge scores -> exp -> store + atomic segment-sum of exp over dst
// ---------------------------------------------------------------------------
__global__ __launch_bounds__(256) void k2_edge(
    const int* __restrict__ ei, const float* __restrict__ asrc,
    const float* __restrict__ adst, float* __restrict__ exp_s,
    float* __restrict__ sum_exp)
{
    int e = blockIdx.x * 256 + threadIdx.x;
    if (e >= NE) return;
    int src = ei[e];
    int dst = ei[NE + e];
    float4 s4 = *(const float4*)(asrc + (size_t)src * 4);
    float4 d4 = *(const float4*)(adst + (size_t)dst * 4);
    float sc0 = s4.x + d4.x;
    float sc1 = s4.y + d4.y;
    float sc2 = s4.z + d4.z;
    float sc3 = s4.w + d4.w;
    sc0 = sc0 >= 0.f ? sc0 : 0.2f * sc0;
    sc1 = sc1 >= 0.f ? sc1 : 0.2f * sc1;
    sc2 = sc2 >= 0.f ? sc2 : 0.2f * sc2;
    sc3 = sc3 >= 0.f ? sc3 : 0.2f * sc3;
    float e0 = __expf(sc0), e1 = __expf(sc1), e2 = __expf(sc2), e3 = __expf(sc3);
    *(float4*)(exp_s + (size_t)e * 4) = make_float4(e0, e1, e2, e3);
    float* sb = sum_exp + (size_t)dst * 4;
    unsafeAtomicAdd(sb + 0, e0);
    unsafeAtomicAdd(sb + 1, e1);
    unsafeAtomicAdd(sb + 2, e2);
    unsafeAtomicAdd(sb + 3, e3);
}

// ---------------------------------------------------------------------------
// k3: out[dst] += (exp/(sum_exp[dst]+eps)) * h[src]; 32 lanes per edge
// ---------------------------------------------------------------------------
__global__ __launch_bounds__(256) void k3_agg(
    const int* __restrict__ ei, const float* __restrict__ hbuf,
    const float* __restrict__ exp_s, const float* __restrict__ sum_exp,
    float* __restrict__ out)
{
    int gid = blockIdx.x * 256 + threadIdx.x;
    int e = gid >> 5;
    if (e >= NE) return;
    int l = gid & 31;
    int src = ei[e];
    int dst = ei[NE + e];
    int head = l >> 3;
    float ex = exp_s[(size_t)e * 4 + head];
    float se = sum_exp[(size_t)dst * 4 + head];
    float w = ex / (se + 1e-16f);
    float4 hv = *(const float4*)(hbuf + (size_t)src * 128 + l * 4);
    float* ob = out + (size_t)dst * 128 + l * 4;
    unsafeAtomicAdd(ob + 0, w * hv.x);
    unsafeAtomicAdd(ob + 1, w * hv.y);
    unsafeAtomicAdd(ob + 2, w * hv.z);
    unsafeAtomicAdd(ob + 3, w * hv.w);
}

// ---------------------------------------------------------------------------
extern "C" void kernel_launch(void* const* d_in, const int* in_sizes, int n_in,
                              void* d_out, int out_size, void* d_ws, size_t ws_size,
                              hipStream_t stream)
{
    const float* X  = (const float*)d_in[0];
    const int*   ei = (const int*)d_in[1];
    const float* W  = (const float*)d_in[2];
    const float* a  = (const float*)d_in[3];
    float* out = (float*)d_out;

    // workspace layout (floats)
    float* hbuf    = (float*)d_ws;            // [NN*128]   = 12,800,000
    float* exp_s   = hbuf + 12800000;         // [NE*4]     =  6,400,000
    float* asrc    = exp_s + 6400000;         // [NN*4]     =    400,000
    float* adst    = asrc + 400000;           // [NN*4]     =    400,000
    float* sum_exp = adst + 400000;           // [NN*4]     =    400,000

    hipMemsetAsync(sum_exp, 0, 400000 * sizeof(float), stream);
    hipMemsetAsync(d_out, 0, (size_t)out_size * sizeof(float), stream);

    k1_gemm_alpha<<<(NN + 255) / 256, 256, 0, stream>>>(X, W, a, hbuf, asrc, adst);
    k2_edge<<<(NE + 255) / 256, 256, 0, stream>>>(ei, asrc, adst, exp_s, sum_exp);
    k3_agg<<<(NE * 32) / 256, 256, 0, stream>>>(ei, hbuf, exp_s, sum_exp, out);
}

// Round 2
// 610.716 us; speedup vs baseline: 5.0643x; 5.0643x over previous
//
#include <hip/hip_runtime.h>

#define NN 100000
#define NE 1600000

static __device__ __forceinline__ unsigned f2bf(float f) {
    unsigned u = __float_as_uint(f);
    return (u + 0x7fffu + ((u >> 16) & 1u)) >> 16;   // RNE
}

// ---------------------------------------------------------------------------
// k1: h = X @ W  (fp32 compute, W in LDS, 4 rows x 32 cols per thread)
//     writes h as bf16 [NN][128]; fused per-node attention partial dots:
//       asrc[n,h] = dot(h[n,h,:], a[h,0:32]),  adst[n,h] = dot(h[n,h,:], a[h,32:64])
// ---------------------------------------------------------------------------
__global__ __launch_bounds__(256) void k1_gemm_alpha(
    const float* __restrict__ X, const float* __restrict__ W,
    const float* __restrict__ a, unsigned short* __restrict__ h16,
    float* __restrict__ asrc, float* __restrict__ adst)
{
    __shared__ float sW[128 * 128];  // 64 KB, swizzled
    {
        const float4* W4 = (const float4*)W;
        float4* sW4 = (float4*)sW;
        #pragma unroll
        for (int i = 0; i < 16; ++i) {
            int idx = threadIdx.x + i * 256;   // 0..4095 float4 granules
            int cg  = idx & 31;                // col granule within k-row
            int k   = idx >> 5;
            int cgs = cg ^ ((cg >> 3) & 3);    // bank swizzle (per col-quarter)
            sW4[(k << 5) + cgs] = W4[idx];
        }
    }
    __syncthreads();

    const int q  = threadIdx.x & 3;   // head / col-quarter (cols q*32..q*32+31)
    const int rg = threadIdx.x >> 2;  // 0..63
    const int row0 = blockIdx.x * 256;

    int rows[4];
    const float4* x4[4];
    #pragma unroll
    for (int i = 0; i < 4; ++i) {
        int r = row0 + rg + i * 64;
        rows[i] = r;
        int rc = r < NN ? r : (NN - 1);
        x4[i] = (const float4*)(X + (size_t)rc * 128);
    }

    float acc[4][32];
    #pragma unroll
    for (int i = 0; i < 4; ++i) {
        #pragma unroll
        for (int c = 0; c < 32; ++c) acc[i][c] = 0.f;
    }

    const float4* sW4r = (const float4*)sW;
    for (int k4 = 0; k4 < 32; ++k4) {
        float xs[4][4];
        #pragma unroll
        for (int i = 0; i < 4; ++i) {
            float4 xv = x4[i][k4];
            xs[i][0] = xv.x; xs[i][1] = xv.y; xs[i][2] = xv.z; xs[i][3] = xv.w;
        }
        #pragma unroll
        for (int j = 0; j < 4; ++j) {
            const int k = (k4 << 2) + j;
            const float4* wr = sW4r + (k << 5) + (q << 3);
            #pragma unroll
            for (int c = 0; c < 8; ++c) {
                float4 wv = wr[c ^ q];  // un-swizzle: logical granule c
                #pragma unroll
                for (int i = 0; i < 4; ++i) {
                    acc[i][(c << 2) + 0] = fmaf(xs[i][j], wv.x, acc[i][(c << 2) + 0]);
                    acc[i][(c << 2) + 1] = fmaf(xs[i][j], wv.y, acc[i][(c << 2) + 1]);
                    acc[i][(c << 2) + 2] = fmaf(xs[i][j], wv.z, acc[i][(c << 2) + 2]);
                    acc[i][(c << 2) + 3] = fmaf(xs[i][j], wv.w, acc[i][(c << 2) + 3]);
                }
            }
        }
    }

    // stage 'a' (256 floats) into LDS (reuse sW; all k-loop reads are done)
    __syncthreads();
    sW[threadIdx.x] = a[threadIdx.x];
    __syncthreads();
    const float* av = sW + q * 64;

    #pragma unroll
    for (int i = 0; i < 4; ++i) {
        if (rows[i] >= NN) continue;
        float ssrc = 0.f, sdst = 0.f;
        #pragma unroll
        for (int c = 0; c < 32; ++c) {
            ssrc = fmaf(acc[i][c], av[c], ssrc);
            sdst = fmaf(acc[i][c], av[32 + c], sdst);
        }
        // pack 32 accs -> 16 uints (bf16x2) -> 4 uint4 stores
        unsigned short* hr = h16 + (size_t)rows[i] * 128 + q * 32;
        uint4* hr4 = (uint4*)hr;
        #pragma unroll
        for (int g = 0; g < 4; ++g) {
            uint4 pk;
            pk.x = f2bf(acc[i][g * 8 + 0]) | (f2bf(acc[i][g * 8 + 1]) << 16);
            pk.y = f2bf(acc[i][g * 8 + 2]) | (f2bf(acc[i][g * 8 + 3]) << 16);
            pk.z = f2bf(acc[i][g * 8 + 4]) | (f2bf(acc[i][g * 8 + 5]) << 16);
            pk.w = f2bf(acc[i][g * 8 + 6]) | (f2bf(acc[i][g * 8 + 7]) << 16);
            hr4[g] = pk;
        }
        asrc[rows[i] * 4 + q] = ssrc;
        adst[rows[i] * 4 + q] = sdst;
    }
}

// ---------------------------------------------------------------------------
// kc: in-degree histogram
// ---------------------------------------------------------------------------
__global__ __launch_bounds__(256) void kc_count(
    const int* __restrict__ ei, int* __restrict__ counts)
{
    int e = blockIdx.x * 256 + threadIdx.x;
    if (e >= NE) return;
    atomicAdd(counts + ei[NE + e], 1);
}

// ---------------------------------------------------------------------------
// kscan: single-block exclusive scan of counts[NN] -> cursor[NN] (row starts)
// ---------------------------------------------------------------------------
#define SCAN_T 1024
#define CHUNK 98   // ceil(100000/1024)
__global__ __launch_bounds__(SCAN_T) void kscan(
    const int* __restrict__ counts, int* __restrict__ cursor)
{
    __shared__ int part[SCAN_T];
    int t = threadIdx.x;
    int beg = t * CHUNK;
    int end = beg + CHUNK; if (end > NN) end = NN;
    int s = 0;
    for (int i = beg; i < end; ++i) s += counts[i];
    part[t] = s;
    __syncthreads();
    for (int off = 1; off < SCAN_T; off <<= 1) {
        int v = (t >= off) ? part[t - off] : 0;
        __syncthreads();
        part[t] += v;
        __syncthreads();
    }
    int run = (t == 0) ? 0 : part[t - 1];
    for (int i = beg; i < end; ++i) { cursor[i] = run; run += counts[i]; }
}

// ---------------------------------------------------------------------------
// k3: scatter edges into CSR slots; compute exp(leakyrelu(score)) on the fly
//     after this kernel: cursor[n] = row_end(n); row_start(n) = cursor[n]-counts[n]
// ---------------------------------------------------------------------------
__global__ __launch_bounds__(256) void k3_scatter(
    const int* __restrict__ ei, const float* __restrict__ asrc,
    const float* __restrict__ adst, int* __restrict__ cursor,
    int* __restrict__ csr_src, float* __restrict__ csr_exp)
{
    int e = blockIdx.x * 256 + threadIdx.x;
    if (e >= NE) return;
    int src = ei[e];
    int dst = ei[NE + e];
    float4 s4 = *(const float4*)(asrc + (size_t)src * 4);
    float4 d4 = *(const float4*)(adst + (size_t)dst * 4);
    float sc0 = s4.x + d4.x;
    float sc1 = s4.y + d4.y;
    float sc2 = s4.z + d4.z;
    float sc3 = s4.w + d4.w;
    sc0 = sc0 >= 0.f ? sc0 : 0.2f * sc0;
    sc1 = sc1 >= 0.f ? sc1 : 0.2f * sc1;
    sc2 = sc2 >= 0.f ? sc2 : 0.2f * sc2;
    sc3 = sc3 >= 0.f ? sc3 : 0.2f * sc3;
    int p = atomicAdd(cursor + dst, 1);
    csr_src[p] = src;
    *(float4*)(csr_exp + (size_t)p * 4) =
        make_float4(__expf(sc0), __expf(sc1), __expf(sc2), __expf(sc3));
}

// ---------------------------------------------------------------------------
// k4: one wave per dst node. pass1: per-head sum of exp; pass2: gather h[src]
//     (bf16), accumulate w*h in registers; one coalesced 512B write per node.
// ---------------------------------------------------------------------------
__global__ __launch_bounds__(256) void k4_agg(
    const int* __restrict__ counts, const int* __restrict__ cursor,
    const int* __restrict__ csr_src, const float* __restrict__ csr_exp,
    const unsigned short* __restrict__ h16, float* __restrict__ out)
{
    int wid = (blockIdx.x * 256 + threadIdx.x) >> 6;
    if (wid >= NN) return;
    int l = threadIdx.x & 63;
    int end = cursor[wid];
    int beg = end - counts[wid];
    int head = l >> 4;                // lane handles cols 2l, 2l+1

    float sum = 0.f;
    for (int i = beg; i < end; ++i) sum += csr_exp[(size_t)i * 4 + head];
    float rs = 1.0f / (sum + 1e-16f);

    float a0 = 0.f, a1 = 0.f;
    for (int i = beg; i < end; ++i) {
        int src = csr_src[i];
        float w = csr_exp[(size_t)i * 4 + head] * rs;
        unsigned hv = *(const unsigned*)(h16 + (size_t)src * 128 + l * 2);
        float h0 = __uint_as_float(hv << 16);
        float h1 = __uint_as_float(hv & 0xffff0000u);
        a0 = fmaf(w, h0, a0);
        a1 = fmaf(w, h1, a1);
    }
    float2* ob = (float2*)(out + (size_t)wid * 128 + l * 2);
    *ob = make_float2(a0, a1);
}

// ---------------------------------------------------------------------------
extern "C" void kernel_launch(void* const* d_in, const int* in_sizes, int n_in,
                              void* d_out, int out_size, void* d_ws, size_t ws_size,
                              hipStream_t stream)
{
    const float* X  = (const float*)d_in[0];
    const int*   ei = (const int*)d_in[1];
    const float* W  = (const float*)d_in[2];
    const float* a  = (const float*)d_in[3];
    float* out = (float*)d_out;

    // workspace layout (4-byte elements), total 15.4M elems = 61.6 MB
    unsigned short* h16 = (unsigned short*)d_ws;          // NN*128 bf16 = 6.4M elems
    float* asrc    = (float*)d_ws + 6400000;              // NN*4
    float* adst    = asrc + 400000;                       // NN*4
    int*   counts  = (int*)(adst + 400000);               // NN
    int*   cursor  = counts + 100000;                     // NN
    int*   csr_src = cursor + 100000;                     // NE
    float* csr_exp = (float*)(csr_src + 1600000);         // NE*4 (16B aligned)

    hipMemsetAsync(counts, 0, NN * sizeof(int), stream);

    k1_gemm_alpha<<<(NN + 255) / 256, 256, 0, stream>>>(X, W, a, h16, asrc, adst);
    kc_count<<<(NE + 255) / 256, 256, 0, stream>>>(ei, counts);
    kscan<<<1, SCAN_T, 0, stream>>>(counts, cursor);
    k3_scatter<<<(NE + 255) / 256, 256, 0, stream>>>(ei, asrc, adst, cursor,
                                                     csr_src, csr_exp);
    k4_agg<<<(NN * 64 + 255) / 256, 256, 0, stream>>>(counts, cursor, csr_src,
                                                      csr_exp, h16, out);
}